// Round 6
// baseline (2771.721 us; speedup 1.0000x reference)
//
#include <hip/hip_runtime.h>
#include <hip/hip_bf16.h>

#define B_   128
#define T_   512
#define D_   512
#define U_   1024
#define O_   512
#define K_   1536      // D + U
#define G4U_ 4096
#define NBLK 256
#define HPITCH 1032    // LDS h-row pitch in shorts (dword stride 516 ≡ 4 mod 32)

typedef __attribute__((ext_vector_type(8))) short short8;
typedef __attribute__((ext_vector_type(4))) float f32x4;
typedef __attribute__((ext_vector_type(4))) int int4v;

__device__ __align__(16) unsigned short g_xbf[(size_t)B_ * T_ * D_];   // x bf16 [b][t][d]
__device__ __align__(16) unsigned short g_Wt[(size_t)G4U_ * K_];       // W^T gate-grouped [cg][k]
__device__ __align__(16) unsigned short g_Wdt[(size_t)O_ * U_];        // Wd^T [o][u]
// h history: slot t holds h_t (slot 0 = h0). Unique slot per step -> cached consumer loads.
__device__ __align__(16) unsigned short g_hall[(size_t)(T_ + 1) * B_ * U_];
// per (logical block, wave) progress flags: block line = 128B, wave slots at 32B spacing
__device__ unsigned int g_flag[NBLK * 32];

__device__ __forceinline__ unsigned short f2b(float f) {
  unsigned u = __float_as_uint(f);
  u += 0x7fffu + ((u >> 16) & 1u);   // RNE
  return (unsigned short)(u >> 16);
}

// fast activations: bf16 output tolerance >> rcp approx error
__device__ __forceinline__ float sigm_f(float x) {
  return __builtin_amdgcn_rcpf(1.f + __expf(-x));
}
__device__ __forceinline__ float tanh_f(float x) {
  // tanh(x) = 1 - 2/(1+e^{2x}); saturates correctly at +/-inf
  return 1.f - 2.f * __builtin_amdgcn_rcpf(1.f + __expf(2.f * x));
}

__global__ void prep_kernel(const float* __restrict__ x, const float* __restrict__ h0,
                            const float* __restrict__ kern, const float* __restrict__ rkern,
                            const float* __restrict__ Wd) {
  size_t tid = (size_t)blockIdx.x * blockDim.x + threadIdx.x;
  size_t np  = (size_t)gridDim.x * blockDim.x;
  if (tid < NBLK * 32) g_flag[tid] = 0u;

  const size_t nx8 = (size_t)B_ * T_ * D_ / 8;
  const float4* xv = (const float4*)x;
  for (size_t i = tid; i < nx8; i += np) {
    float4 v0 = xv[2 * i], v1 = xv[2 * i + 1];
    unsigned short tmp[8];
    tmp[0] = f2b(v0.x); tmp[1] = f2b(v0.y); tmp[2] = f2b(v0.z); tmp[3] = f2b(v0.w);
    tmp[4] = f2b(v1.x); tmp[5] = f2b(v1.y); tmp[6] = f2b(v1.z); tmp[7] = f2b(v1.w);
    *(int4*)&g_xbf[i * 8] = *(const int4*)tmp;
  }

  // W layout (verified r1/r2): row cg = (u>>4)*64 + gate*16 + (u&15), k contiguous
  const size_t nw = (size_t)G4U_ * (K_ / 8);
  for (size_t i = tid; i < nw; i += np) {
    size_t cg = i / (K_ / 8);
    int kb = (int)(i % (K_ / 8)) * 8;
    int c = (int)(cg >> 6), g = (int)((cg >> 4) & 3), j = (int)(cg & 15);
    int n = g * 1024 + (c << 4) + j;
    unsigned short tmp[8];
#pragma unroll
    for (int q = 0; q < 8; ++q) {
      int k = kb + q;
      float v = (k < 512) ? kern[(size_t)k * G4U_ + n] : rkern[(size_t)(k - 512) * G4U_ + n];
      tmp[q] = f2b(v);
    }
    *(int4*)&g_Wt[cg * K_ + kb] = *(const int4*)tmp;
  }

  const size_t nd = (size_t)O_ * (U_ / 8);
  for (size_t i = tid; i < nd; i += np) {
    int o  = (int)(i >> 7);
    int ub = (int)(i & 127) * 8;
    unsigned short tmp[8];
#pragma unroll
    for (int q = 0; q < 8; ++q) tmp[q] = f2b(Wd[(size_t)(ub + q) * O_ + o]);
    *(int4*)&g_Wdt[(size_t)o * U_ + ub] = *(const int4*)tmp;
  }

  const size_t nh = (size_t)B_ * U_;
  for (size_t i = tid; i < nh; i += np) g_hall[i] = f2b(h0[i]);  // slot 0 = h0
}

// 256 persistent blocks x 256 threads, 1 block/CU. XCD-clustered mapping (r3-proven).
// R6: per-WAVE publication + pipelined half-consume.
//  - Producer: each wave stores its 8 rows x 16 cols of h_{t+1}, waits ITS OWN
//    vmcnt(0) (inline asm, no block barrier), then stores flag[lb][wave].
//  - Consumer wave: quarter = 16 producers x 4 wave-flags = 64 flags; split in 2
//    halves of 8 producers. spinA -> issue A loads -> spinB (A fill in flight) ->
//    issue B loads -> LDS-write A -> MFMA A -> LDS-write B -> MFMA B.
//  - 2 block barriers/iter (zpo, po). zpo/po reuse hazards are separated by the
//    alternating po-bar(t)/zpo-bar(t+1); t=0 has no out phase -> one extra barrier.
// x path: register fragments prefetched in prior iteration; x-MFMAs pre-poll.
// All weights register-resident (VGPR+AGPR unified file).
__global__ __launch_bounds__(256, 1) void lstm_kernel(const float* __restrict__ c0,
                                                      const float* __restrict__ bias,
                                                      const float* __restrict__ bd,
                                                      float* __restrict__ out) {
  const int b    = blockIdx.x;
  const int tid  = threadIdx.x;
  const int wq   = tid >> 6;
  const int lane = tid & 63;
  const int rg   = lane >> 4;
  const int fr   = lane & 15;

  // XCD-clustered logical ids
  const int xcd = b & 7, idx = b >> 3;
  const int mg  = xcd >> 1;            // row group 0..3
  const int sl  = idx * 2 + (xcd & 1); // u-tile 0..63
  const int lb  = mg * 64 + sl;        // logical id (flag line index)
  const int m0  = mg * 32;
  const int ug  = sl;
  const int u0  = ug * 16;

  __shared__ __align__(16) unsigned short Ast[32 * HPITCH];   // 66 KB: staged h_t
  __shared__ f32x4 zpo[4][32][17];                            // 34 KB z partials (padded)
  __shared__ float po[4][16][20];                             // 5 KB out partials

  // ---------- one-time weight preload into registers ----------
  short8 wzx[4][4], wzh[8][4];
#pragma unroll
  for (int kt = 0; kt < 4; ++kt)
#pragma unroll
    for (int g = 0; g < 4; ++g)
      wzx[kt][g] = *(const short8*)&g_Wt[(size_t)(ug * 64 + g * 16 + fr) * K_ +
                                         wq * 128 + kt * 32 + rg * 8];
#pragma unroll
  for (int kt = 0; kt < 8; ++kt)
#pragma unroll
    for (int g = 0; g < 4; ++g)
      wzh[kt][g] = *(const short8*)&g_Wt[(size_t)(ug * 64 + g * 16 + fr) * K_ +
                                         512 + wq * 256 + kt * 32 + rg * 8];

  const int oc0 = (ug >> 1) * 16;   // out col tile
  const int orh = (ug & 1) * 16;    // out row half
  short8 wd[8];
#pragma unroll
  for (int kt = 0; kt < 8; ++kt)
    wd[kt] = *(const short8*)&g_Wdt[(size_t)(oc0 + fr) * U_ + wq * 256 + kt * 32 + rg * 8];

  // ---------- per-thread gate-element mapping ----------
  const int erow = tid >> 3;
  const int euu  = (tid & 7) * 2;
  float cv[2];
  f32x4 bv[2];
#pragma unroll
  for (int j = 0; j < 2; ++j) {
    cv[j] = c0[(size_t)(m0 + erow) * U_ + u0 + euu + j];
    f32x4 tv;
#pragma unroll
    for (int g = 0; g < 4; ++g) tv[g] = bias[g * 1024 + u0 + euu + j];
    bv[j] = tv;
  }

  const int orow = tid >> 4, ocl = tid & 15;
  const float bd_v = bd[oc0 + ocl];

  const int xcol = wq * 128 + rg * 8;   // per-wave x K-chunk column base
  // LDS A-fragment pointers (wave-private h quarter)
  const unsigned short* ahp0 = &Ast[(size_t)fr * HPITCH + wq * 256 + rg * 8];
  const unsigned short* ahp1 = ahp0 + 16 * HPITCH;
  const unsigned short* aop  = &Ast[(size_t)(orh + fr) * HPITCH + wq * 256 + rg * 8];

  // per-wave half-staging map: instr q covers rows {4q..4q+3}, 256B bursts per row
  const int srow4 = lane >> 4;         // 0..3  row within quad
  const int sseg  = lane & 15;         // 16B segment within the 256B half-row-slice

  // prologue: x fragments for t=0
  short8 axf0[4], axf1[4];
  {
    const unsigned short* x0 = &g_xbf[((size_t)(m0 + fr) * T_ + 0) * D_ + xcol];
    const unsigned short* x1 = &g_xbf[((size_t)(m0 + 16 + fr) * T_ + 0) * D_ + xcol];
#pragma unroll
    for (int kt = 0; kt < 4; ++kt) {
      axf0[kt] = *(const short8*)&x0[kt * 32];
      axf1[kt] = *(const short8*)&x1[kt * 32];
    }
  }

  for (int t = 0; t <= T_; ++t) {
    f32x4 acc[2][4];
    if (t < T_) {
      // ---------- x-part MFMAs from registers: no dependency on the flags ----------
#pragma unroll
      for (int rt = 0; rt < 2; ++rt)
#pragma unroll
        for (int g = 0; g < 4; ++g) acc[rt][g] = (f32x4){0.f, 0.f, 0.f, 0.f};
#pragma unroll
      for (int kt = 0; kt < 4; ++kt)
#pragma unroll
        for (int g = 0; g < 4; ++g) {
          acc[0][g] = __builtin_amdgcn_mfma_f32_16x16x32_bf16(axf0[kt], wzx[kt][g], acc[0][g], 0, 0, 0);
          acc[1][g] = __builtin_amdgcn_mfma_f32_16x16x32_bf16(axf1[kt], wzx[kt][g], acc[1][g], 0, 0, 0);
        }
    }

    const size_t hb = (size_t)t * (B_ * U_);
    int4v bhA[8], bhB[8];

    // ---------- spin half A (producers wq*16..+8, all 4 wave-flags) ----------
    if (t > 0) {
      if (lane < 32) {
        unsigned int* fp = &g_flag[(mg * 64 + wq * 16 + (lane >> 2)) * 32 + (lane & 3) * 8];
        while (__hip_atomic_load(fp, __ATOMIC_RELAXED, __HIP_MEMORY_SCOPE_AGENT) <
               (unsigned)t)
          __builtin_amdgcn_s_sleep(1);
      }
      asm volatile("" ::: "memory");
    }
    // ---------- issue A loads (cols [wq*256, +128)) ----------
#pragma unroll
    for (int q = 0; q < 8; ++q)
      bhA[q] = *(const int4v*)&g_hall[hb + (size_t)(m0 + 4 * q + srow4) * U_ +
                                     wq * 256 + sseg * 8];

    // ---------- spin half B (producers wq*16+8..+16); A fill in flight ----------
    if (t > 0) {
      if (lane < 32) {
        unsigned int* fp = &g_flag[(mg * 64 + wq * 16 + 8 + (lane >> 2)) * 32 + (lane & 3) * 8];
        while (__hip_atomic_load(fp, __ATOMIC_RELAXED, __HIP_MEMORY_SCOPE_AGENT) <
               (unsigned)t)
          __builtin_amdgcn_s_sleep(1);
      }
      asm volatile("" ::: "memory");
    }
    // ---------- issue B loads (cols [wq*256+128, +128)) ----------
#pragma unroll
    for (int q = 0; q < 8; ++q)
      bhB[q] = *(const int4v*)&g_hall[hb + (size_t)(m0 + 4 * q + srow4) * U_ +
                                     wq * 256 + 128 + sseg * 8];

    // ---------- LDS-write A, MFMA A (kt 0..4) while B in flight ----------
#pragma unroll
    for (int q = 0; q < 8; ++q)
      *(int4v*)&Ast[(size_t)(4 * q + srow4) * HPITCH + wq * 256 + sseg * 8] = bhA[q];
    if (t < T_) {
#pragma unroll
      for (int kt = 0; kt < 4; ++kt) {
        short8 a0 = *(const short8*)&ahp0[kt * 32];
        short8 a1 = *(const short8*)&ahp1[kt * 32];
#pragma unroll
        for (int g = 0; g < 4; ++g) {
          acc[0][g] = __builtin_amdgcn_mfma_f32_16x16x32_bf16(a0, wzh[kt][g], acc[0][g], 0, 0, 0);
          acc[1][g] = __builtin_amdgcn_mfma_f32_16x16x32_bf16(a1, wzh[kt][g], acc[1][g], 0, 0, 0);
        }
      }
    }
    // ---------- LDS-write B, MFMA B (kt 4..8) ----------
#pragma unroll
    for (int q = 0; q < 8; ++q)
      *(int4v*)&Ast[(size_t)(4 * q + srow4) * HPITCH + wq * 256 + 128 + sseg * 8] = bhB[q];
    if (t < T_) {
#pragma unroll
      for (int kt = 4; kt < 8; ++kt) {
        short8 a0 = *(const short8*)&ahp0[kt * 32];
        short8 a1 = *(const short8*)&ahp1[kt * 32];
#pragma unroll
        for (int g = 0; g < 4; ++g) {
          acc[0][g] = __builtin_amdgcn_mfma_f32_16x16x32_bf16(a0, wzh[kt][g], acc[0][g], 0, 0, 0);
          acc[1][g] = __builtin_amdgcn_mfma_f32_16x16x32_bf16(a1, wzh[kt][g], acc[1][g], 0, 0, 0);
        }
      }

      // partials -> LDS: one f32x4 (i,f,g,o) per (row, u) element
#pragma unroll
      for (int rt = 0; rt < 2; ++rt)
#pragma unroll
        for (int r = 0; r < 4; ++r) {
          f32x4 v = {acc[rt][0][r], acc[rt][1][r], acc[rt][2][r], acc[rt][3][r]};
          zpo[wq][rt * 16 + rg * 4 + r][fr] = v;
        }
      __syncthreads();   // zpo-bar

      // ---------- K-reduce + gates (fast activations) + packed h store ----------
      {
        unsigned short* hn = &g_hall[(size_t)(t + 1) * (B_ * U_)];
        float hv[2];
#pragma unroll
        for (int j = 0; j < 2; ++j) {
          f32x4 z = zpo[0][erow][euu + j] + zpo[1][erow][euu + j] +
                    zpo[2][erow][euu + j] + zpo[3][erow][euu + j];
          z += bv[j];
          float ig = sigm_f(z[0]);
          float fg = sigm_f(z[1]);
          float gg = tanh_f(z[2]);
          float og = sigm_f(z[3]);
          cv[j] = fg * cv[j] + ig * gg;
          hv[j] = og * tanh_f(cv[j]);
        }
        unsigned int pk = (unsigned)f2b(hv[0]) | ((unsigned)f2b(hv[1]) << 16);
        *(volatile unsigned int*)&hn[(size_t)(m0 + erow) * U_ + u0 + euu] = pk;
      }

      // ---------- per-WAVE publish: own vmcnt drain, then own flag ----------
      asm volatile("s_waitcnt vmcnt(0)" ::: "memory");
      if (lane == 0)
        __hip_atomic_store(&g_flag[lb * 32 + wq * 8], (unsigned)(t + 1),
                           __ATOMIC_RELAXED, __HIP_MEMORY_SCOPE_AGENT);

      // ---------- prefetch x fragments for t+1 (off critical path) ----------
      if (t + 1 < T_) {
        const unsigned short* x0 = &g_xbf[((size_t)(m0 + fr) * T_ + (t + 1)) * D_ + xcol];
        const unsigned short* x1 = &g_xbf[((size_t)(m0 + 16 + fr) * T_ + (t + 1)) * D_ + xcol];
#pragma unroll
        for (int kt = 0; kt < 4; ++kt) {
          axf0[kt] = *(const short8*)&x0[kt * 32];
          axf1[kt] = *(const short8*)&x1[kt * 32];
        }
      }
      if (t == 0) __syncthreads();   // protect zpo reuse (no po-bar in iter 0)
    }

    // ---------- out[t-1] = h_t @ Wd + bd from my staged LDS quarter ----------
    if (t > 0) {
      f32x4 oa = {0.f, 0.f, 0.f, 0.f};
#pragma unroll
      for (int kt = 0; kt < 8; ++kt)
        oa = __builtin_amdgcn_mfma_f32_16x16x32_bf16(*(const short8*)&aop[kt * 32],
                                                     wd[kt], oa, 0, 0, 0);
#pragma unroll
      for (int r = 0; r < 4; ++r) po[wq][rg * 4 + r][fr] = oa[r];
      __syncthreads();   // po-bar
      float v = po[0][orow][ocl] + po[1][orow][ocl] + po[2][orow][ocl] +
                po[3][orow][ocl] + bd_v;
      out[((size_t)(m0 + orh + orow) * T_ + (t - 1)) * O_ + oc0 + ocl] = v;
    }
  }
}

extern "C" void kernel_launch(void* const* d_in, const int* in_sizes, int n_in,
                              void* d_out, int out_size, void* d_ws, size_t ws_size,
                              hipStream_t stream) {
  const float* x    = (const float*)d_in[0];
  const float* h0   = (const float*)d_in[1];
  const float* c0   = (const float*)d_in[2];
  const float* kern = (const float*)d_in[3];
  const float* rk   = (const float*)d_in[4];
  const float* bias = (const float*)d_in[5];
  const float* Wd   = (const float*)d_in[6];
  const float* bd   = (const float*)d_in[7];
  float* out = (float*)d_out;
  (void)in_sizes; (void)n_in; (void)d_ws; (void)ws_size; (void)out_size;

  prep_kernel<<<dim3(1024), dim3(256), 0, stream>>>(x, h0, kern, rk, Wd);
  lstm_kernel<<<dim3(NBLK), dim3(256), 0, stream>>>(c0, bias, bd, out);
}